// Round 3
// 357.125 us; speedup vs baseline: 1.0014x; 1.0014x over previous
//
#include <hip/hip_runtime.h>
#include <math.h>

// Problem constants (from reference)
#define B_ROWS 65536
#define C_COLS 1024
#define GRID_BLOCKS 2048
#define BLOCK_THREADS 256
#define WAVES_PER_BLOCK (BLOCK_THREADS / 64)

__device__ __forceinline__ float softplus(float x) {
    // log1p(exp(x)), numerically stable for large |x|
    float ax = fabsf(x);
    return fmaxf(x, 0.0f) + log1pf(expf(-ax));
}

// Fold one float4 chunk into the running negative-max.
// j = label - 4*c4 : position of the positive within this float4 (if 0..3).
// No arrays, no dynamic indexing -> pure v_cmp/v_cndmask, no scratch.
__device__ __forceinline__ void consume(float4 v, int j, float& spos, float& m) {
    if ((unsigned)j < 4u) {
        // extract positive score via select tree
        float s01 = (j & 1) ? v.y : v.x;
        float s23 = (j & 1) ? v.w : v.z;
        spos = (j & 2) ? s23 : s01;
        // exclude positive from the negative max
        v.x = (j == 0) ? -INFINITY : v.x;
        v.y = (j == 1) ? -INFINITY : v.y;
        v.z = (j == 2) ? -INFINITY : v.z;
        v.w = (j == 3) ? -INFINITY : v.w;
    }
    m = fmaxf(m, fmaxf(fmaxf(v.x, v.y), fmaxf(v.z, v.w)));
}

__global__ __launch_bounds__(BLOCK_THREADS) void rank_loss_partial(
        const float* __restrict__ scores,
        const int* __restrict__ labels,
        double* __restrict__ partials) {
    const int waveId = threadIdx.x >> 6;
    const int lane = threadIdx.x & 63;
    const int globalWave = blockIdx.x * WAVES_PER_BLOCK + waveId;
    const int totalWaves = GRID_BLOCKS * WAVES_PER_BLOCK;

    const float MARGIN_POS = 2.5f;
    const float MARGIN_NEG = 0.5f;
    const float GAMMA = 2.0f;

    double acc = 0.0;  // per-LANE accumulator (summed at block end)
    for (int row = globalWave; row < B_ROWS; row += totalWaves) {
        const int label = labels[row];
        const float4* __restrict__ rowp =
            (const float4*)(scores + (size_t)row * C_COLS);

        // Issue all 4 coalesced loads up front (4 KB/row in flight per wave).
        float4 v0 = rowp[lane];
        float4 v1 = rowp[lane + 64];
        float4 v2 = rowp[lane + 128];
        float4 v3 = rowp[lane + 192];

        float m = -INFINITY;     // max over negative classes
        float spos = 0.0f;       // positive score (valid only on owner lane)

        consume(v0, label - (lane << 2),          spos, m);
        consume(v1, label - ((lane + 64) << 2),   spos, m);
        consume(v2, label - ((lane + 128) << 2),  spos, m);
        consume(v3, label - ((lane + 192) << 2),  spos, m);

        // butterfly max-reduce of m across the 64-lane wave (only chain needed)
        #pragma unroll
        for (int off = 32; off > 0; off >>= 1)
            m = fmaxf(m, __shfl_xor(m, off, 64));

        // owner lane of the positive element accumulates loss_pos locally
        if (lane == ((label >> 2) & 63)) {
            acc += (double)softplus(GAMMA * (MARGIN_POS - spos));
        }
        // lane 0 accumulates loss_neg
        if (lane == 0) {
            float sneg = (label == 0) ? 0.0f : m;
            acc += (double)softplus(GAMMA * (MARGIN_NEG + sneg));
        }
    }

    // wave-level sum of per-lane accumulators
    #pragma unroll
    for (int off = 32; off > 0; off >>= 1)
        acc += __shfl_down(acc, off, 64);

    __shared__ double sacc[WAVES_PER_BLOCK];
    if (lane == 0) sacc[waveId] = acc;
    __syncthreads();
    if (threadIdx.x == 0) {
        double s = 0.0;
        #pragma unroll
        for (int i = 0; i < WAVES_PER_BLOCK; ++i) s += sacc[i];
        partials[blockIdx.x] = s;
    }
}

__global__ __launch_bounds__(256) void rank_loss_final(
        const double* __restrict__ partials, float* __restrict__ out) {
    __shared__ double sdata[256];
    double s = 0.0;
    for (int i = threadIdx.x; i < GRID_BLOCKS; i += 256) s += partials[i];
    sdata[threadIdx.x] = s;
    __syncthreads();
    #pragma unroll
    for (int off = 128; off > 0; off >>= 1) {
        if (threadIdx.x < off) sdata[threadIdx.x] += sdata[threadIdx.x + off];
        __syncthreads();
    }
    if (threadIdx.x == 0) out[0] = (float)(sdata[0] / (double)B_ROWS);
}

extern "C" void kernel_launch(void* const* d_in, const int* in_sizes, int n_in,
                              void* d_out, int out_size, void* d_ws, size_t ws_size,
                              hipStream_t stream) {
    const float* scores = (const float*)d_in[0];
    const int* labels = (const int*)d_in[1];
    float* out = (float*)d_out;
    double* partials = (double*)d_ws;  // GRID_BLOCKS doubles = 16 KB

    rank_loss_partial<<<GRID_BLOCKS, BLOCK_THREADS, 0, stream>>>(scores, labels, partials);
    rank_loss_final<<<1, 256, 0, stream>>>(partials, out);
}

// Round 4
// 357.045 us; speedup vs baseline: 1.0016x; 1.0002x over previous
//
#include <hip/hip_runtime.h>
#include <math.h>

// Problem constants (from reference)
#define B_ROWS 65536
#define C_COLS 1024
#define GRID_BLOCKS 2048
#define BLOCK_THREADS 256
#define WAVES_PER_BLOCK (BLOCK_THREADS / 64)
#define TOTAL_WAVES (GRID_BLOCKS * WAVES_PER_BLOCK)   // 8192
#define ROWS_PER_WAVE (B_ROWS / TOTAL_WAVES)          // exactly 8

__device__ __forceinline__ float softplus(float x) {
    // log1p(exp(x)), numerically stable for large |x|
    float ax = fabsf(x);
    return fmaxf(x, 0.0f) + log1pf(expf(-ax));
}

// Fold one float4 chunk into the running negative-max.
// j = label - 4*c4 : position of the positive within this float4 (if 0..3).
// Branchless select tree -> no arrays, no scratch.
__device__ __forceinline__ void consume(float4 v, int j, float& spos, float& m) {
    if ((unsigned)j < 4u) {
        float s01 = (j & 1) ? v.y : v.x;
        float s23 = (j & 1) ? v.w : v.z;
        spos = (j & 2) ? s23 : s01;
        v.x = (j == 0) ? -INFINITY : v.x;
        v.y = (j == 1) ? -INFINITY : v.y;
        v.z = (j == 2) ? -INFINITY : v.z;
        v.w = (j == 3) ? -INFINITY : v.w;
    }
    m = fmaxf(m, fmaxf(fmaxf(v.x, v.y), fmaxf(v.z, v.w)));
}

// __launch_bounds__(256, 4): cap VGPR at 128 -> >=4 waves/SIMD (16 waves/CU)
// while leaving room for the unrolled loads to pipeline across rows.
__global__ __launch_bounds__(BLOCK_THREADS, 4) void rank_loss_partial(
        const float* __restrict__ scores,
        const int* __restrict__ labels,
        double* __restrict__ partials) {
    const int waveId = threadIdx.x >> 6;
    const int lane = threadIdx.x & 63;
    const int wave = blockIdx.x * WAVES_PER_BLOCK + waveId;

    const float MARGIN_POS = 2.5f;
    const float MARGIN_NEG = 0.5f;
    const float GAMMA = 2.0f;

    // Preload all 8 wave-uniform labels up front (independent of score stream).
    int lab[ROWS_PER_WAVE];
    #pragma unroll
    for (int k = 0; k < ROWS_PER_WAVE; ++k)
        lab[k] = labels[wave + k * TOTAL_WAVES];

    double acc = 0.0;       // per-lane accumulator
    float spos_mine = 0.0f; // lane k holds row k's positive score
    float sneg_mine = 0.0f; // lane k holds row k's negative max

    // Exactly 8 iterations (8192 waves x 8 rows = 65536): full unroll lets the
    // scheduler issue row k+1's loads under row k's shuffle chain.
    #pragma unroll
    for (int k = 0; k < ROWS_PER_WAVE; ++k) {
        const int row = wave + k * TOTAL_WAVES;
        const int label = lab[k];
        const float4* __restrict__ rowp =
            (const float4*)(scores + (size_t)row * C_COLS);

        float4 v0 = rowp[lane];
        float4 v1 = rowp[lane + 64];
        float4 v2 = rowp[lane + 128];
        float4 v3 = rowp[lane + 192];

        float m = -INFINITY;
        float spos = 0.0f;

        consume(v0, label - (lane << 2),          spos, m);
        consume(v1, label - ((lane + 64) << 2),   spos, m);
        consume(v2, label - ((lane + 128) << 2),  spos, m);
        consume(v3, label - ((lane + 192) << 2),  spos, m);

        // butterfly max-reduce across the 64-lane wave (all lanes get m)
        #pragma unroll
        for (int off = 32; off > 0; off >>= 1)
            m = fmaxf(m, __shfl_xor(m, off, 64));

        // pull the positive score from its owner lane; lane k archives row k
        float spos_k = __shfl(spos, (label >> 2) & 63, 64);
        float sneg   = (label == 0) ? 0.0f : m;
        if (lane == k) { spos_mine = spos_k; sneg_mine = sneg; }
    }

    // Lanes 0..7 each evaluate ONE row's softplus pair in parallel
    // (replaces 8 serial divergent lane-0 tails).
    if (lane < ROWS_PER_WAVE) {
        acc += (double)softplus(GAMMA * (MARGIN_POS - spos_mine))
             + (double)softplus(GAMMA * (MARGIN_NEG + sneg_mine));
    }

    // wave-level sum of per-lane accumulators
    #pragma unroll
    for (int off = 32; off > 0; off >>= 1)
        acc += __shfl_down(acc, off, 64);

    __shared__ double sacc[WAVES_PER_BLOCK];
    if (lane == 0) sacc[waveId] = acc;
    __syncthreads();
    if (threadIdx.x == 0) {
        double s = 0.0;
        #pragma unroll
        for (int i = 0; i < WAVES_PER_BLOCK; ++i) s += sacc[i];
        partials[blockIdx.x] = s;
    }
}

__global__ __launch_bounds__(256) void rank_loss_final(
        const double* __restrict__ partials, float* __restrict__ out) {
    __shared__ double sdata[256];
    double s = 0.0;
    for (int i = threadIdx.x; i < GRID_BLOCKS; i += 256) s += partials[i];
    sdata[threadIdx.x] = s;
    __syncthreads();
    #pragma unroll
    for (int off = 128; off > 0; off >>= 1) {
        if (threadIdx.x < off) sdata[threadIdx.x] += sdata[threadIdx.x + off];
        __syncthreads();
    }
    if (threadIdx.x == 0) out[0] = (float)(sdata[0] / (double)B_ROWS);
}

extern "C" void kernel_launch(void* const* d_in, const int* in_sizes, int n_in,
                              void* d_out, int out_size, void* d_ws, size_t ws_size,
                              hipStream_t stream) {
    const float* scores = (const float*)d_in[0];
    const int* labels = (const int*)d_in[1];
    float* out = (float*)d_out;
    double* partials = (double*)d_ws;  // GRID_BLOCKS doubles = 16 KB

    rank_loss_partial<<<GRID_BLOCKS, BLOCK_THREADS, 0, stream>>>(scores, labels, partials);
    rank_loss_final<<<1, 256, 0, stream>>>(partials, out);
}